// Round 2
// baseline (456.508 us; speedup 1.0000x reference)
//
#include <hip/hip_runtime.h>
#include <hip/hip_fp16.h>

// ---------------- small prep kernels ----------------

__global__ void k_zero_deg(int* __restrict__ deg, int N) {
  int i = blockIdx.x * blockDim.x + threadIdx.x;
  if (i < N) deg[i] = 0;
}

__global__ void k_count_deg(const int* __restrict__ col, int E, int* __restrict__ deg) {
  int stride = gridDim.x * blockDim.x;
  for (int i = blockIdx.x * blockDim.x + threadIdx.x; i < E; i += stride)
    atomicAdd(&deg[col[i]], 1);
}

__global__ void k_prep(const int* __restrict__ deg, const float* __restrict__ x,
                       float* __restrict__ dinv, float* __restrict__ xd, int N) {
  int i = blockIdx.x * blockDim.x + threadIdx.x;
  if (i < N) {
    float d = rsqrtf((float)deg[i] + 1.0f);  // +1 self-loop
    dinv[i] = d;
    xd[i] = x[i] * d;
  }
}

// ---------------- prefix-sum (CSR offsets) ----------------

__global__ void k_scan1(const int* __restrict__ deg, int N, int* __restrict__ off,
                        int* __restrict__ bsum) {
  __shared__ int wsum[4];
  int i = blockIdx.x * 256 + threadIdx.x;
  int lane = threadIdx.x & 63, wid = threadIdx.x >> 6;
  int v = (i < N) ? deg[i] : 0;
  int inc = v;
  #pragma unroll
  for (int d = 1; d < 64; d <<= 1) { int t = __shfl_up(inc, d); if (lane >= d) inc += t; }
  if (lane == 63) wsum[wid] = inc;
  __syncthreads();
  if (threadIdx.x == 0) {
    int a = 0;
    for (int w = 0; w < 4; ++w) { int t = wsum[w]; wsum[w] = a; a += t; }
    bsum[blockIdx.x] = a;
  }
  __syncthreads();
  if (i < N) off[i] = inc - v + wsum[wid];  // block-local exclusive
}

__global__ void k_scan2(const int* __restrict__ bsum, int nb, int* __restrict__ boff) {
  __shared__ int wsum[8];
  int lane = threadIdx.x & 63, wid = threadIdx.x >> 6;
  int i = threadIdx.x;
  int v = (i < nb) ? bsum[i] : 0;
  int inc = v;
  #pragma unroll
  for (int d = 1; d < 64; d <<= 1) { int t = __shfl_up(inc, d); if (lane >= d) inc += t; }
  if (lane == 63) wsum[wid] = inc;
  __syncthreads();
  if (threadIdx.x == 0) {
    int a = 0;
    for (int w = 0; w < 8; ++w) { int t = wsum[w]; wsum[w] = a; a += t; }
  }
  __syncthreads();
  if (i < nb) boff[i] = inc - v + wsum[wid];
}

__global__ void k_scan3(int* __restrict__ off, int* __restrict__ pos,
                        const int* __restrict__ boff, int N, int E) {
  int i = blockIdx.x * 256 + threadIdx.x;
  if (i < N) {
    int o = off[i] + boff[blockIdx.x];
    off[i] = o;
    pos[i] = o;
  }
  if (i == 0) off[N] = E;
}

__global__ void k_scatter(const int* __restrict__ ei, int E,
                          int* __restrict__ pos, int* __restrict__ csr) {
  int stride = gridDim.x * blockDim.x;
  for (int e = blockIdx.x * blockDim.x + threadIdx.x; e < E; e += stride) {
    int src = ei[e];
    int dst = ei[E + e];
    int slot = atomicAdd(&pos[dst], 1);
    csr[slot] = src;
  }
}

// ---------------- conv1: scalar aggregation ----------------

__global__ void k_agg1(const int* __restrict__ off, const int* __restrict__ csr,
                       const float* __restrict__ xd, const float* __restrict__ dinv,
                       float* __restrict__ s, int N) {
  int v = blockIdx.x * blockDim.x + threadIdx.x;
  if (v >= N) return;
  int beg = off[v], end = off[v + 1];
  float sum = xd[v];  // self-loop: x[v]*dinv[v]
  for (int i = beg; i < end; ++i) sum += xd[csr[i]];
  s[v] = dinv[v] * sum;
}

// ---------------- gemm: ys[v][h] = fp16( dinv[v] * (relu(W2*s[v]+b2) @ W3)[h] ) ----------------

#define GEMM_NODES 64
__global__ __launch_bounds__(256) void k_gemm(
    const float* __restrict__ s, const float* __restrict__ dinv,
    const float* __restrict__ W2, const float* __restrict__ b2,
    const float* __restrict__ W3, __half* __restrict__ ys, int N) {
  __shared__ float h1s[GEMM_NODES * 128];  // 32 KB
  __shared__ float sv[GEMM_NODES];
  __shared__ float dv[GEMM_NODES];
  int base = blockIdx.x * GEMM_NODES;
  int t = threadIdx.x;
  if (t < GEMM_NODES) {
    int v = base + t;
    sv[t] = (v < N) ? s[v] : 0.f;
    dv[t] = (v < N) ? dinv[v] : 0.f;
  }
  __syncthreads();
  for (int idx = t; idx < GEMM_NODES * 128; idx += 256) {
    int nn = idx >> 7, k = idx & 127;
    float h1 = fmaf(W2[k], sv[nn], b2[k]);
    h1s[idx] = h1 > 0.f ? h1 : 0.f;
  }
  __syncthreads();
  int h = t & 127;
  int nbase = (t >> 7) * 32;
  float acc[32];
  #pragma unroll
  for (int n = 0; n < 32; ++n) acc[n] = 0.f;
  for (int k4 = 0; k4 < 32; ++k4) {
    int k = k4 * 4;
    float wa = W3[(k + 0) * 128 + h];
    float wb = W3[(k + 1) * 128 + h];
    float wc = W3[(k + 2) * 128 + h];
    float wd = W3[(k + 3) * 128 + h];
    #pragma unroll
    for (int n = 0; n < 32; ++n) {
      const float4 hv = *(const float4*)&h1s[(nbase + n) * 128 + k];
      float a = acc[n];
      a = fmaf(hv.x, wa, a);
      a = fmaf(hv.y, wb, a);
      a = fmaf(hv.z, wc, a);
      a = fmaf(hv.w, wd, a);
      acc[n] = a;
    }
  }
  #pragma unroll
  for (int n = 0; n < 32; ++n) {
    int v = base + nbase + n;
    if (v < N) ys[(size_t)v * 128 + h] = __float2half_rn(acc[n] * dv[nbase + n]);
  }
}

// ---------------- graph meta: counts via binary search + out init ----------------

__global__ void k_meta(const int* __restrict__ batch, int N, int G,
                       const float* __restrict__ lin_b, int C,
                       float* __restrict__ invcnt, float* __restrict__ out) {
  for (int g = threadIdx.x; g < G; g += blockDim.x) {
    int lo = 0, hi = N;
    while (lo < hi) { int mid = (lo + hi) >> 1; if (batch[mid] < g) lo = mid + 1; else hi = mid; }
    int start = lo;
    lo = 0; hi = N;
    while (lo < hi) { int mid = (lo + hi) >> 1; if (batch[mid] < g + 1) lo = mid + 1; else hi = mid; }
    int cnt = lo - start;
    invcnt[g] = 1.0f / (float)(cnt > 0 ? cnt : 1);
  }
  for (int idx = threadIdx.x; idx < G * C; idx += blockDim.x)
    out[idx] = lin_b[idx % C];  // reset every call; atomics accumulate on top
}

// ---------------- conv2 + relu + project + pooled atomic add ----------------

__global__ __launch_bounds__(256) void k_conv2(
    const __half* __restrict__ ys, const int* __restrict__ off, const int* __restrict__ csr,
    const float* __restrict__ dinv, const float* __restrict__ b3,
    const float* __restrict__ lin_w, const int* __restrict__ batch,
    const float* __restrict__ invcnt, float* __restrict__ out, int N) {
  int wid = threadIdx.x >> 6, lane = threadIdx.x & 63;
  int v = blockIdx.x * 4 + wid;
  if (v >= N) return;
  const __half2* ysh = (const __half2*)ys;  // row stride 64 in half2 units
  int beg = off[v], end = off[v + 1];
  // self term: ys row already scaled by dinv[src]
  float2 a0 = __half22float2(ysh[(size_t)v * 64 + lane]);
  float2 a1 = {0.f, 0.f}, a2 = {0.f, 0.f}, a3 = {0.f, 0.f};
  for (int c0 = beg; c0 < end; c0 += 64) {
    int m = end - c0; if (m > 64) m = 64;
    int myu = (lane < m) ? csr[c0 + lane] : 0;
    int j = 0;
    for (; j + 4 <= m; j += 4) {
      int u0 = __shfl(myu, j);
      int u1 = __shfl(myu, j + 1);
      int u2 = __shfl(myu, j + 2);
      int u3 = __shfl(myu, j + 3);
      float2 t0 = __half22float2(ysh[(size_t)u0 * 64 + lane]);
      float2 t1 = __half22float2(ysh[(size_t)u1 * 64 + lane]);
      float2 t2 = __half22float2(ysh[(size_t)u2 * 64 + lane]);
      float2 t3 = __half22float2(ysh[(size_t)u3 * 64 + lane]);
      a0.x += t0.x; a0.y += t0.y;
      a1.x += t1.x; a1.y += t1.y;
      a2.x += t2.x; a2.y += t2.y;
      a3.x += t3.x; a3.y += t3.y;
    }
    for (; j < m; ++j) {
      int u = __shfl(myu, j);
      float2 t = __half22float2(ysh[(size_t)u * 64 + lane]);
      a0.x += t.x; a0.y += t.y;
    }
  }
  float accx = a0.x + a1.x + a2.x + a3.x;
  float accy = a0.y + a1.y + a2.y + a3.y;
  float dv = dinv[v];
  float h2a = fmaf(accx, dv, b3[lane * 2 + 0]); h2a = h2a > 0.f ? h2a : 0.f;
  float h2b = fmaf(accy, dv, b3[lane * 2 + 1]); h2b = h2b > 0.f ? h2b : 0.f;
  // project to 16 classes
  float z[16];
  const float* lwa = lin_w + (lane * 2 + 0) * 16;
  const float* lwb = lin_w + (lane * 2 + 1) * 16;
  #pragma unroll
  for (int c = 0; c < 16; ++c) z[c] = h2a * lwa[c] + h2b * lwb[c];
  #pragma unroll
  for (int d = 32; d > 0; d >>= 1) {
    #pragma unroll
    for (int c = 0; c < 16; ++c) z[c] += __shfl_xor(z[c], d);
  }
  int g = batch[v];
  float ic = invcnt[g];
  if (lane < 16) atomicAdd(&out[g * 16 + lane], z[lane] * ic);
}

// ---------------- launch ----------------

extern "C" void kernel_launch(void* const* d_in, const int* in_sizes, int n_in,
                              void* d_out, int out_size, void* d_ws, size_t ws_size,
                              hipStream_t stream) {
  const float* x = (const float*)d_in[0];
  const int* ei = (const int*)d_in[1];      // int32 per harness convention
  const int* batch = (const int*)d_in[2];   // int32
  const float* W2 = (const float*)d_in[4];
  const float* b2 = (const float*)d_in[5];
  const float* W3 = (const float*)d_in[6];
  const float* b3 = (const float*)d_in[7];
  const float* lin_w = (const float*)d_in[8];
  const float* lin_b = (const float*)d_in[9];
  float* out = (float*)d_out;

  int N = in_sizes[0];       // 100000
  int E = in_sizes[1] / 2;   // 1600000
  int C = in_sizes[9];       // 16
  int G = out_size / C;      // 512

  char* p = (char*)d_ws;
  auto take = [&](size_t bytes) {
    char* r = p;
    p += (bytes + 255) & ~(size_t)255;
    return r;
  };
  int* deg = (int*)take((size_t)N * 4);
  int* off = (int*)take((size_t)(N + 1) * 4);
  int* pos = (int*)take((size_t)N * 4);
  int* bsum = (int*)take(4096);
  int* boff = (int*)take(4096);
  float* dinv = (float*)take((size_t)N * 4);
  float* xd = (float*)take((size_t)N * 4);
  float* s = (float*)take((size_t)N * 4);
  float* invcnt = (float*)take((size_t)G * 4);
  int* csr = (int*)take((size_t)E * 4);
  __half* ys = (__half*)take((size_t)N * 128 * 2);  // fp16 intermediate, 25.6 MB

  int nb = (N + 255) / 256;  // 391 (fits k_scan2's 512 threads)

  hipLaunchKernelGGL(k_zero_deg, dim3((N + 255) / 256), dim3(256), 0, stream, deg, N);
  hipLaunchKernelGGL(k_count_deg, dim3(2048), dim3(256), 0, stream, ei + E, E, deg);
  hipLaunchKernelGGL(k_prep, dim3((N + 255) / 256), dim3(256), 0, stream, deg, x, dinv, xd, N);
  hipLaunchKernelGGL(k_scan1, dim3(nb), dim3(256), 0, stream, deg, N, off, bsum);
  hipLaunchKernelGGL(k_scan2, dim3(1), dim3(512), 0, stream, bsum, nb, boff);
  hipLaunchKernelGGL(k_scan3, dim3(nb), dim3(256), 0, stream, off, pos, boff, N, E);
  hipLaunchKernelGGL(k_scatter, dim3(2048), dim3(256), 0, stream, ei, E, pos, csr);
  hipLaunchKernelGGL(k_agg1, dim3((N + 255) / 256), dim3(256), 0, stream, off, csr, xd, dinv, s, N);
  hipLaunchKernelGGL(k_gemm, dim3((N + GEMM_NODES - 1) / GEMM_NODES), dim3(256), 0, stream,
                     s, dinv, W2, b2, W3, ys, N);
  hipLaunchKernelGGL(k_meta, dim3(1), dim3(512), 0, stream, batch, N, G, lin_b, C, invcnt, out);
  hipLaunchKernelGGL(k_conv2, dim3((N + 3) / 4), dim3(256), 0, stream,
                     ys, off, csr, dinv, b3, lin_w, batch, invcnt, out, N);
}